// Round 5
// baseline (559.260 us; speedup 1.0000x reference)
//
#include <hip/hip_runtime.h>

// ---------------------------------------------------------------------------
// GraphSAGE 3-layer, bf16 pipeline.
// Round 5: XCD-L2 locality round.
//   - aggregation: feature-sliced by XCD (blockIdx%8) -> per-XCD working set
//     3.2MB < 4MB L2 (was: 25.6MB random-gathered by all XCDs)
//   - CSR build: dst-range partitioned by XCD -> cursor+col stay L2-local
//   - layer 2 keeps the agg(h@Wl2) reorder (64-dim gathers, 2 slices)
// ---------------------------------------------------------------------------

typedef short bf16x8 __attribute__((ext_vector_type(8)));
typedef float f32x4 __attribute__((ext_vector_type(4)));

__device__ __forceinline__ unsigned short f2bf(float f) {
    unsigned int b = __float_as_uint(f);
    b += 0x7fffu + ((b >> 16) & 1u);
    return (unsigned short)(b >> 16);
}
__device__ __forceinline__ float bflo(unsigned int u) { return __uint_as_float(u << 16); }
__device__ __forceinline__ float bfhi(unsigned int u) { return __uint_as_float(u & 0xffff0000u); }

__device__ __forceinline__ void gload_lds16(const void* g, void* l) {
    __builtin_amdgcn_global_load_lds(
        (const __attribute__((address_space(1))) void*)g,
        (__attribute__((address_space(3))) void*)l, 16, 0, 0);
}

// ---------------- CSR build (XCD dst-range partitioned) ----------------
__global__ __launch_bounds__(256) void count_deg_part_kernel(
        const int* __restrict__ ei, int* __restrict__ deg, int E, int n, int chunkSz) {
    const int part = blockIdx.x & 7;
    const int chunk = blockIdx.x >> 3;
    const int lo = (int)(((long long)part * n) >> 3);
    const int hi = (int)(((long long)(part + 1) * n) >> 3);
    const int e0 = chunk * chunkSz;
    const int e1 = min(e0 + chunkSz, E);
    for (int e = e0 + threadIdx.x; e < e1; e += 256) {
        int d = ei[E + e];
        if (d >= lo && d < hi) atomicAdd(&deg[d], 1);
    }
}

// per-block inclusive scan of deg -> incl, block sums -> bsum
__global__ __launch_bounds__(1024) void scan1_kernel(
        const int* __restrict__ deg, int* __restrict__ incl, int* __restrict__ bsum, int n) {
    __shared__ int wsum[16];
    __shared__ int woff[16];
    const int tid = threadIdx.x, lane = tid & 63, wid = tid >> 6;
    int i = blockIdx.x * 1024 + tid;
    int x = (i < n) ? deg[i] : 0;
    #pragma unroll
    for (int off = 1; off < 64; off <<= 1) {
        int t = __shfl_up(x, off, 64);
        if (lane >= off) x += t;
    }
    if (lane == 63) wsum[wid] = x;
    __syncthreads();
    if (tid == 0) {
        int s = 0;
        #pragma unroll
        for (int w = 0; w < 16; ++w) { woff[w] = s; s += wsum[w]; }
        bsum[blockIdx.x] = s;
    }
    __syncthreads();
    if (i < n) incl[i] = x + woff[wid];
}

__global__ void scan2_kernel(int* __restrict__ bsum, int nb) {
    int lane = threadIdx.x;
    int v = (lane < nb) ? bsum[lane] : 0;
    int x = v;
    #pragma unroll
    for (int off = 1; off < 64; off <<= 1) {
        int t = __shfl_up(x, off, 64);
        if (lane >= off) x += t;
    }
    if (lane < nb) bsum[lane] = x - v;   // exclusive
}

// writes row_ptr AND cursor (= row_ptr[0..n-1]) so no d2d copy is needed
__global__ void scan3_kernel(const int* __restrict__ incl, const int* __restrict__ bsum,
                             int* __restrict__ row_ptr, int* __restrict__ cursor, int n) {
    int i = blockIdx.x * blockDim.x + threadIdx.x;
    if (i == 0) { row_ptr[0] = 0; cursor[0] = 0; }
    if (i < n) {
        int v = incl[i] + bsum[i >> 10];
        row_ptr[i + 1] = v;
        if (i + 1 < n) cursor[i + 1] = v;
    }
}

__global__ __launch_bounds__(256) void fill_csr_part_kernel(
        const int* __restrict__ ei, int* __restrict__ cursor, int* __restrict__ col,
        int E, int n, int chunkSz) {
    const int part = blockIdx.x & 7;
    const int chunk = blockIdx.x >> 3;
    const int lo = (int)(((long long)part * n) >> 3);
    const int hi = (int)(((long long)(part + 1) * n) >> 3);
    const int e0 = chunk * chunkSz;
    const int e1 = min(e0 + chunkSz, E);
    for (int e = e0 + threadIdx.x; e < e1; e += 256) {
        int d = ei[E + e];
        if (d >= lo && d < hi) {
            int s = ei[e];
            int pos = atomicAdd(&cursor[d], 1);
            col[pos] = s;
        }
    }
}

// ---------------- converts ----------------
__global__ void cvt_bf16_kernel(const float* __restrict__ x, unsigned short* __restrict__ y, int n4) {
    int i = blockIdx.x * blockDim.x + threadIdx.x;
    if (i < n4) {
        float4 v = ((const float4*)x)[i];
        ushort4 o;
        o.x = f2bf(v.x); o.y = f2bf(v.y); o.z = f2bf(v.z); o.w = f2bf(v.w);
        ((ushort4*)y)[i] = o;
    }
}

// BT[n][k] = (k<256 ? Wl[k][n] : Wr[k-256][n]) bf16; K=512 concat
__global__ void build_bt_kernel(const float* __restrict__ Wl, const float* __restrict__ Wr,
                                unsigned short* __restrict__ BT, int N) {
    int id = blockIdx.x * blockDim.x + threadIdx.x;
    if (id >= N * 512) return;
    int k = id / N;
    int n = id - k * N;
    float v = (k < 256) ? Wl[(size_t)k * N + n] : Wr[(size_t)(k - 256) * N + n];
    BT[(size_t)n * 512 + k] = f2bf(v);
}

// single W [256][N] -> BT [N][256]
__global__ void build_bt1_kernel(const float* __restrict__ W, unsigned short* __restrict__ BT, int N) {
    int id = blockIdx.x * blockDim.x + threadIdx.x;
    if (id >= N * 256) return;
    int k = id / N;
    int n = id - k * N;
    BT[(size_t)n * 256 + k] = f2bf(W[(size_t)k * N + n]);
}

// ---------------- XCD feature-sliced aggregation ----------------
// Slice s = 32 features (64B of a row). blockIdx%8 -> XCD -> slice group, so
// each XCD's gather working set is DIM/SLICES*2B*N rows (3.2MB) -> L2-resident.
// Per wave: one node; 4 edge-groups of 16 lanes; lane loads 4B (2 bf16).
template<int DIM, int SLICES, bool OUT_BF16>
__global__ __launch_bounds__(256) void aggregate_sliced_kernel(
        const unsigned short* __restrict__ h, const int* __restrict__ row_ptr,
        const int* __restrict__ col, void* __restrict__ agg, int n) {
    constexpr int F = DIM / SLICES;        // 32 features per slice
    constexpr int BPS = 8 / SLICES;        // sub-chunks sharing a slice
    constexpr int NPC = BPS * 4;           // nodes per chunk (4 waves/block)
    const int bid = blockIdx.x;
    const int xcd = bid & 7;
    const int chunk = bid >> 3;
    const int slice = xcd / BPS;
    const int sub = xcd % BPS;
    const int wid = threadIdx.x >> 6;
    const int lane = threadIdx.x & 63;
    const int node = chunk * NPC + sub * 4 + wid;
    if (node >= n) return;
    const int start = row_ptr[node], end = row_ptr[node + 1];
    const int g = lane >> 4;               // edge group 0..3
    const int fo = slice * F + (lane & 15) * 2;
    float a0 = 0.f, a1 = 0.f;
    int eb = start;
    for (; eb + 8 <= end; eb += 8) {
        int c0 = col[eb + g], c1 = col[eb + 4 + g];
        unsigned v0 = *(const unsigned*)(h + (size_t)c0 * DIM + fo);
        unsigned v1 = *(const unsigned*)(h + (size_t)c1 * DIM + fo);
        a0 += bflo(v0) + bflo(v1);
        a1 += bfhi(v0) + bfhi(v1);
    }
    for (; eb < end; eb += 4) {
        int e = eb + g;
        if (e < end) {
            unsigned v = *(const unsigned*)(h + (size_t)col[e] * DIM + fo);
            a0 += bflo(v); a1 += bfhi(v);
        }
    }
    a0 += __shfl_xor(a0, 16, 64); a1 += __shfl_xor(a1, 16, 64);
    a0 += __shfl_xor(a0, 32, 64); a1 += __shfl_xor(a1, 32, 64);
    int d = end - start;
    float inv = 1.0f / (float)(d > 1 ? d : 1);
    if (lane < 16) {
        if (OUT_BF16) {
            unsigned packed = (unsigned)f2bf(a0 * inv) | ((unsigned)f2bf(a1 * inv) << 16);
            *(unsigned*)((unsigned short*)agg + (size_t)node * DIM + fo) = packed;
        } else {
            float2 o = make_float2(a0 * inv, a1 * inv);
            *(float2*)((float*)agg + (size_t)node * DIM + fo) = o;
        }
    }
}

// ---------------- fused MFMA GEMM ----------------
// C = [A0|A1](M x NKS*32) @ BT^T (+bias) (+add) (+relu); BT is [Nc'][NKS*32] bf16.
// A rows are always 256-wide. BM=128, BN=NT*32, BK=32; 4 waves (2x2).
template<int NKS, int NT, bool RELU, bool OUT_BF16, bool HAS_BIAS, bool HAS_ADD>
__global__ __launch_bounds__(256) void gemm_mfma_kernel(
        const unsigned short* __restrict__ A0, const unsigned short* __restrict__ A1,
        const unsigned short* __restrict__ BT, const float* __restrict__ bias,
        const float* __restrict__ add, void* __restrict__ Cout, int M, int Nc) {
    constexpr int BN = NT * 32;
    constexpr int KB = NKS * 32;           // BT row stride (elems)
    __shared__ unsigned short As[128 * 32];
    __shared__ unsigned short Bs[BN * 32];
    const int tid = threadIdx.x;
    const int lane = tid & 63;
    const int wid = tid >> 6;
    const int wr = wid >> 1, wc = wid & 1;
    const int row0 = blockIdx.x * 128;
    const int col0 = blockIdx.y * BN;

    f32x4 acc[4][NT];
    #pragma unroll
    for (int i = 0; i < 4; ++i)
        #pragma unroll
        for (int j = 0; j < NT; ++j) acc[i][j] = (f32x4){0.f, 0.f, 0.f, 0.f};

    const int rA = tid >> 2;
    const int kc = (tid & 3) * 8;

    for (int ks = 0; ks < NKS; ++ks) {
        const unsigned short* Asrc = (NKS == 16) ? (ks < 8 ? A0 : A1) : A0;
        const int ka = (NKS == 16) ? ((ks & 7) * 32) : (ks * 32);
        #pragma unroll
        for (int i = 0; i < 2; ++i) {
            const unsigned short* g = Asrc + (size_t)(row0 + rA + i * 64) * 256 + ka + kc;
            gload_lds16(g, As + (size_t)i * 2048 + tid * 8);
        }
        #pragma unroll
        for (int i = 0; i < NT / 2; ++i) {
            const unsigned short* g = BT + (size_t)(col0 + rA + i * 64) * KB + ks * 32 + kc;
            gload_lds16(g, Bs + (size_t)i * 2048 + tid * 8);
        }
        __syncthreads();

        bf16x8 a[4], b[NT];
        #pragma unroll
        for (int tm = 0; tm < 4; ++tm)
            a[tm] = *(const bf16x8*)&As[(wr * 64 + tm * 16 + (lane & 15)) * 32 + (lane >> 4) * 8];
        #pragma unroll
        for (int tn = 0; tn < NT; ++tn)
            b[tn] = *(const bf16x8*)&Bs[(wc * NT * 16 + tn * 16 + (lane & 15)) * 32 + (lane >> 4) * 8];
        #pragma unroll
        for (int tm = 0; tm < 4; ++tm)
            #pragma unroll
            for (int tn = 0; tn < NT; ++tn)
                acc[tm][tn] = __builtin_amdgcn_mfma_f32_16x16x32_bf16(a[tm], b[tn], acc[tm][tn], 0, 0, 0);
        __syncthreads();
    }

    const int cb = col0 + wc * NT * 16;
    #pragma unroll
    for (int tn = 0; tn < NT; ++tn) {
        int colg = cb + tn * 16 + (lane & 15);
        float bv = HAS_BIAS ? bias[colg] : 0.f;
        #pragma unroll
        for (int tm = 0; tm < 4; ++tm) {
            #pragma unroll
            for (int r = 0; r < 4; ++r) {
                int row = row0 + wr * 64 + tm * 16 + (lane >> 4) * 4 + r;
                if (row < M) {
                    float v = acc[tm][tn][r] + bv;
                    if (HAS_ADD) v += add[(size_t)row * Nc + colg];
                    if (RELU) v = fmaxf(v, 0.f);
                    if (OUT_BF16)
                        ((unsigned short*)Cout)[(size_t)row * Nc + colg] = f2bf(v);
                    else
                        ((float*)Cout)[(size_t)row * Nc + colg] = v;
                }
            }
        }
    }
}

extern "C" void kernel_launch(void* const* d_in, const int* in_sizes, int n_in,
                              void* d_out, int out_size, void* d_ws, size_t ws_size,
                              hipStream_t stream) {
    const float* x   = (const float*)d_in[0];
    const int*   ei  = (const int*)d_in[1];
    const float* Wl0 = (const float*)d_in[2];
    const float* Wr0 = (const float*)d_in[3];
    const float* b0  = (const float*)d_in[4];
    const float* Wl1 = (const float*)d_in[5];
    const float* Wr1 = (const float*)d_in[6];
    const float* b1  = (const float*)d_in[7];
    const float* Wl2 = (const float*)d_in[8];
    const float* Wr2 = (const float*)d_in[9];
    const float* b2  = (const float*)d_in[10];
    float* out = (float*)d_out;

    const int Nn = in_sizes[0] / 256;          // 50000
    const int E  = in_sizes[1] / 2;            // 800000
    const int Mpad = ((Nn + 127) / 128) * 128; // 50048
    const int nb = (Nn + 1023) / 1024;         // scan blocks (49)

    char* ws = (char*)d_ws;
    size_t off = 0;
    auto take = [&](size_t bytes) -> void* {
        void* p = (void*)(ws + off);
        off += (bytes + 255) & ~(size_t)255;
        return p;
    };
    int* deg     = (int*)take((size_t)Nn * 4);
    int* incl    = (int*)take((size_t)Nn * 4);
    int* bsum    = (int*)take((size_t)64 * 4);
    int* row_ptr = (int*)take((size_t)(Nn + 1) * 4);
    int* cursor  = (int*)take((size_t)Nn * 4);
    int* col     = (int*)take((size_t)E * 4);
    unsigned short* xb  = (unsigned short*)take((size_t)Mpad * 256 * 2);
    unsigned short* h1  = (unsigned short*)take((size_t)Mpad * 256 * 2);
    unsigned short* h2  = (unsigned short*)take((size_t)Mpad * 256 * 2);
    unsigned short* h3  = (unsigned short*)take((size_t)Mpad * 256 * 2);
    unsigned short* p2  = (unsigned short*)take((size_t)Mpad * 64 * 2);
    float* aggp = (float*)take((size_t)Mpad * 64 * 4);
    unsigned short* BT0  = (unsigned short*)take((size_t)256 * 512 * 2);
    unsigned short* BT1  = (unsigned short*)take((size_t)256 * 512 * 2);
    unsigned short* BT2l = (unsigned short*)take((size_t)64 * 256 * 2);
    unsigned short* BT2r = (unsigned short*)take((size_t)64 * 256 * 2);
    (void)ws_size; (void)n_in; (void)out_size;

    // ---- CSR build (XCD dst-partitioned) ----
    const int chunkSz = 1024;
    const int echunks = (E + chunkSz - 1) / chunkSz;
    hipMemsetAsync(deg, 0, (size_t)Nn * 4, stream);
    count_deg_part_kernel<<<echunks * 8, 256, 0, stream>>>(ei, deg, E, Nn, chunkSz);
    scan1_kernel<<<nb, 1024, 0, stream>>>(deg, incl, bsum, Nn);
    scan2_kernel<<<1, 64, 0, stream>>>(bsum, nb);
    scan3_kernel<<<(Nn + 255) / 256, 256, 0, stream>>>(incl, bsum, row_ptr, cursor, Nn);
    fill_csr_part_kernel<<<echunks * 8, 256, 0, stream>>>(ei, cursor, col, E, Nn, chunkSz);

    // ---- converts ----
    cvt_bf16_kernel<<<(Nn * 64 + 255) / 256, 256, 0, stream>>>(x, xb, Nn * 64);
    build_bt_kernel<<<(256 * 512 + 255) / 256, 256, 0, stream>>>(Wl0, Wr0, BT0, 256);
    build_bt_kernel<<<(256 * 512 + 255) / 256, 256, 0, stream>>>(Wl1, Wr1, BT1, 256);
    build_bt1_kernel<<<(64 * 256 + 255) / 256, 256, 0, stream>>>(Wl2, BT2l, 64);
    build_bt1_kernel<<<(64 * 256 + 255) / 256, 256, 0, stream>>>(Wr2, BT2r, 64);

    const int gx = Mpad / 128;
    const int aggGrid256 = ((Nn + 3) / 4) * 8;      // NPC=4, 8 slices
    const int aggGrid64  = ((Nn + 15) / 16) * 8;    // NPC=16, 2 slices x 4 sub

    // ---- layer 0 ----
    aggregate_sliced_kernel<256, 8, true><<<aggGrid256, 256, 0, stream>>>(xb, row_ptr, col, h1, Nn);
    gemm_mfma_kernel<16, 4, true, true, true, false><<<dim3(gx, 2), 256, 0, stream>>>(
        h1, xb, BT0, b0, nullptr, h2, Nn, 256);
    // ---- layer 1 ----
    aggregate_sliced_kernel<256, 8, true><<<aggGrid256, 256, 0, stream>>>(h2, row_ptr, col, h1, Nn);
    gemm_mfma_kernel<16, 4, true, true, true, false><<<dim3(gx, 2), 256, 0, stream>>>(
        h1, h2, BT1, b1, nullptr, h3, Nn, 256);
    // ---- layer 2: agg(h3)@Wl2 == agg(h3@Wl2) ----
    gemm_mfma_kernel<8, 2, false, true, false, false><<<dim3(gx, 1), 256, 0, stream>>>(
        h3, nullptr, BT2l, nullptr, nullptr, p2, Nn, 64);
    aggregate_sliced_kernel<64, 2, false><<<aggGrid64, 256, 0, stream>>>(p2, row_ptr, col, aggp, Nn);
    gemm_mfma_kernel<8, 2, false, false, true, true><<<dim3(gx, 1), 256, 0, stream>>>(
        h3, nullptr, BT2r, b2, aggp, out, Nn, 64);
}